// Round 6
// baseline (573.195 us; speedup 1.0000x reference)
//
#include <hip/hip_runtime.h>
#include <math.h>

#define T_LEN 1024
#define BATCH 512
#define DIN   12
#define HID   100
#define G4    400
#define MB    4                   // batches per block, at C-rows {0,4,8,12}
#define NBLK  (BATCH / MB)        // 128
#define AROW  136                 // halves per A row (k 0..127 + pad)
#define NW    8
#define NTHR  (NW * 64)           // 512
#define CHUNK 64
#define UNROLL 8

typedef _Float16 half8   __attribute__((ext_vector_type(8)));
typedef _Float16 half4_t __attribute__((ext_vector_type(4)));
typedef float    f32x4   __attribute__((ext_vector_type(4)));

static __device__ __forceinline__ float fast_exp2(float v) {
#if __has_builtin(__builtin_amdgcn_exp2f)
    return __builtin_amdgcn_exp2f(v);
#else
    return exp2f(v);
#endif
}
static __device__ __forceinline__ float fast_rcp(float v) {
#if __has_builtin(__builtin_amdgcn_rcpf)
    return __builtin_amdgcn_rcpf(v);
#else
    return 1.0f / v;
#endif
}

// Waves 0-6: gate columns j = wid*16 + (lane&15), j<100; batches at C-rows
// {0,4,8,12} -> cell state entirely in C-register 0 (1-reg activation).
// A-rows 1-3,5-7,... are never meaningful: every lane reads row (l>>2) of a
// 4-row A buffer -> 4-way same-address broadcast, NO bank conflicts, 4x less
// LDS zero/footprint. Wave 7: output projection (Wd) + x staging + stores.
__launch_bounds__(NTHR, 2)
__global__ void lstm_mfma_kernel(const float* __restrict__ x,
                                 const float* __restrict__ Wx,
                                 const float* __restrict__ Wh,
                                 const float* __restrict__ b,
                                 const float* __restrict__ Wd,
                                 const float* __restrict__ bd,
                                 float* __restrict__ out) {
    __shared__ __align__(16) char smem[65536];
    const int tid  = threadIdx.x;
    const int wid  = tid >> 6;
    const int lane = tid & 63;
    const int l    = lane & 15;
    const int quad = lane >> 4;
    const int b0   = blockIdx.x * MB;
    const int j    = wid * 16 + l;

    // ---------- prologue: B fragments staged through LDS (defeats remat-sinking) ----------
    _Float16* stage = (_Float16*)smem;      // [8][8][512] halves = 64 KB
    half8 bfrag[4][4];                       // wave 7 uses only bfrag[0] (= Wd cols)
#pragma unroll
    for (int pass = 0; pass < 2; ++pass) {
#pragma unroll
        for (int gg = 0; gg < 2; ++gg) {
            const int G = pass * 2 + gg;
#pragma unroll
            for (int kt = 0; kt < 4; ++kt) {
                half8 v;
#pragma unroll
                for (int jj = 0; jj < 8; ++jj) {
                    const int k = kt * 32 + quad * 8 + jj;
                    float w = 0.f;
                    if (wid < 7) {
                        if (j < HID) {
                            if (k < HID)            w = Wh[k * G4 + G * HID + j];
                            else if (k < HID + DIN) w = Wx[(k - HID) * G4 + G * HID + j];
                        }
                    } else if (G == 0) {
                        if (l < DIN && k < HID)     w = Wd[k * DIN + l];
                    }
                    v[jj] = (_Float16)w;
                }
                *(half8*)&stage[((wid * 8) + (gg * 4 + kt)) * 512 + lane * 8] = v;
            }
        }
        __syncthreads();
#pragma unroll
        for (int gg = 0; gg < 2; ++gg)
#pragma unroll
            for (int kt = 0; kt < 4; ++kt)
                bfrag[pass * 2 + gg][kt] =
                    *(half8*)&stage[((wid * 8) + (gg * 4 + kt)) * 512 + lane * 8];
        __syncthreads();
    }

    float biasv[4] = {0.f, 0.f, 0.f, 0.f};
    if (wid < 7) {
        if (j < HID) {
#pragma unroll
            for (int G = 0; G < 4; ++G) biasv[G] = b[G * HID + j];
        }
    } else if (l < DIN) {
        biasv[0] = bd[l];
    }

    // ---------- LDS after prologue: 4-row A dbuf + x chunk ----------
    _Float16 (*Ah)[MB][AROW] = (_Float16 (*)[MB][AROW])smem;     // 2*4*136*2 = 2176 B
    _Float16* xchunk = (_Float16*)(smem + 2176);                 // 64*48*2 = 6144 B

    auto refill = [&](int c) {    // x[c*64 .. +63] for 4 batches -> fp16 LDS
#pragma unroll
        for (int ii = 0; ii < 2; ++ii) {
            const int f = tid + NTHR * ii;
            if (f < (CHUNK * MB * DIN) / 4) {                    // 768 float4s
                const int m  = f / (CHUNK * DIN / 4);            // /192
                const int o  = f - m * (CHUNK * DIN / 4);
                const int tt = o / 3;
                const int dd = o - tt * 3;
                const float4 v = *(const float4*)(x +
                    ((size_t)(b0 + m) * T_LEN + c * CHUNK + tt) * DIN + dd * 4);
                half4_t h4;
                h4[0] = (_Float16)v.x; h4[1] = (_Float16)v.y;
                h4[2] = (_Float16)v.z; h4[3] = (_Float16)v.w;
                *(half4_t*)&xchunk[tt * (MB * DIN) + m * DIN + dd * 4] = h4;
            }
        }
    };

    for (int i = tid; i < (2 * MB * AROW) / 2; i += NTHR) ((int*)smem)[i] = 0;
    refill(0);
    __syncthreads();
    if (tid < MB * 3) {           // stage x[0]
        const int m = tid / 3, part = tid - (tid / 3) * 3;
        *(half4_t*)&Ah[0][m][HID + part * 4] =
            *(const half4_t*)&xchunk[m * DIN + part * 4];
    }
    __syncthreads();

    const bool gate_lane = (wid < 7) && (j < HID);
    const int  arow = l >> 2;     // broadcast row: lanes of a quad-group share it
    const float L2E = 1.4426950408889634f;

    float c = 0.f;                // cell state (C-reg 0, batch = quad)
    float obuf[UNROLL];

#pragma unroll 1
    for (int tb = 0; tb <= T_LEN / UNROLL; ++tb) {
#pragma unroll
        for (int it = 0; it < UNROLL; ++it) {
            const int t = tb * UNROLL + it;
            if (t <= T_LEN) {
                const int p = t & 1, pn = p ^ 1;
                if (((t + 1) & (CHUNK - 1)) == 0 && (t + 1) < T_LEN) {
                    refill((t + 1) >> 6);
                    __syncthreads();
                }
                half8 a[4];
#pragma unroll
                for (int kt = 0; kt < 4; ++kt)
                    a[kt] = *(const half8*)&Ah[p][arow][kt * 32 + quad * 8];

                if (wid < 7) {
                    f32x4 acc[4];
#pragma unroll
                    for (int G = 0; G < 4; ++G) {
                        const float bv = biasv[G];
                        acc[G] = (f32x4){bv, bv, bv, bv};
                    }
                    // kt outer / G inner: dependent MFMAs are 4 apart -> latency hidden
#pragma unroll
                    for (int kt = 0; kt < 4; ++kt)
#pragma unroll
                        for (int G = 0; G < 4; ++G)
                            acc[G] = __builtin_amdgcn_mfma_f32_16x16x32_f16(
                                         a[kt], bfrag[G][kt], acc[G], 0, 0, 0);

                    if (t < T_LEN && gate_lane) {
                        // combined-reciprocal LSTM cell (reg 0 only)
                        const float ei = fast_exp2(-L2E * acc[0][0]);
                        const float ef = fast_exp2(-L2E * acc[1][0]);
                        const float eg = fast_exp2(-2.f * L2E * acc[2][0]);
                        const float eo = fast_exp2(-L2E * acc[3][0]);
                        const float gig = (1.f - eg) * fast_rcp((1.f + ei) * (1.f + eg));
                        const float gf  = fast_rcp(1.f + ef);
                        const float cn  = gf * c + gig;
                        c = cn;
                        const float ec = fast_exp2(-2.f * L2E * cn);
                        const float hv = (1.f - ec) * fast_rcp((1.f + eo) * (1.f + ec));
                        Ah[pn][quad][j] = (_Float16)hv;
                    }
                } else {
                    f32x4 accP = {biasv[0], biasv[0], biasv[0], biasv[0]};
#pragma unroll
                    for (int kt = 0; kt < 4; ++kt)
                        accP = __builtin_amdgcn_mfma_f32_16x16x32_f16(
                                   a[kt], bfrag[0][kt], accP, 0, 0, 0);
                    obuf[it] = accP[0];               // out row t-1, batch=quad, col=l
                    if ((t + 1) < T_LEN && lane < MB * 3) {   // stage x[t+1]
                        const int m = lane / 3, part = lane - (lane / 3) * 3;
                        *(half4_t*)&Ah[pn][m][HID + part * 4] =
                            *(const half4_t*)&xchunk[((t + 1) & (CHUNK - 1)) * (MB * DIN)
                                                     + m * DIN + part * 4];
                    }
                }
                __syncthreads();
            }
        }
        if (wid == 7 && l < DIN) {
#pragma unroll
            for (int s = 0; s < UNROLL; ++s) {
                const int row = tb * UNROLL + s - 1;
                if (row >= 0 && row < T_LEN)
                    out[((size_t)(b0 + quad) * T_LEN + row) * DIN + l] = obuf[s];
            }
        }
    }
}

extern "C" void kernel_launch(void* const* d_in, const int* in_sizes, int n_in,
                              void* d_out, int out_size, void* d_ws, size_t ws_size,
                              hipStream_t stream) {
    const float* x  = (const float*)d_in[0];
    const float* Wx = (const float*)d_in[1];
    const float* Wh = (const float*)d_in[2];
    const float* b  = (const float*)d_in[3];
    const float* Wd = (const float*)d_in[4];
    const float* bd = (const float*)d_in[5];
    float* out = (float*)d_out;

    lstm_mfma_kernel<<<NBLK, NTHR, 0, stream>>>(x, Wx, Wh, b, Wd, bd, out);
}

// Round 7
// 538.011 us; speedup vs baseline: 1.0654x; 1.0654x over previous
//
#include <hip/hip_runtime.h>
#include <math.h>

#define T_LEN 1024
#define BATCH 512
#define DIN   12
#define HID   100
#define G4    400
#define MB    4                   // batches per block, at C-rows {0,4,8,12}
#define NBLK  (BATCH / MB)        // 128
#define AROW  160                 // halves per A row -> 320 B = 80 dwords = 16 mod 32 (2-way banks, free)
#define NW    8
#define NTHR  (NW * 64)           // 512
#define CHUNK 64
#define UNROLL 8

typedef _Float16 half8   __attribute__((ext_vector_type(8)));
typedef _Float16 half4_t __attribute__((ext_vector_type(4)));
typedef float    f32x4   __attribute__((ext_vector_type(4)));

static __device__ __forceinline__ float fast_exp2(float v) {
#if __has_builtin(__builtin_amdgcn_exp2f)
    return __builtin_amdgcn_exp2f(v);
#else
    return exp2f(v);
#endif
}
static __device__ __forceinline__ float fast_rcp(float v) {
#if __has_builtin(__builtin_amdgcn_rcpf)
    return __builtin_amdgcn_rcpf(v);
#else
    return 1.0f / v;
#endif
}

// Waves 0-6: gate columns j = wid*16 + (lane&15), j<100; batches at C-rows
// {0,4,8,12} -> cell state entirely in C-register 0 (1-reg activation).
// Lanes read A-row (l>>2); with 320B row stride all chunks are 2-way banked (free).
// Bias lives in persistent f32x4 regs used as the C operand of the first MFMA
// of each chain -> zero per-step accumulator init.
// Wave 7: output projection (Wd) + x staging + batched stores.
__launch_bounds__(NTHR, 2)
__global__ void lstm_mfma_kernel(const float* __restrict__ x,
                                 const float* __restrict__ Wx,
                                 const float* __restrict__ Wh,
                                 const float* __restrict__ b,
                                 const float* __restrict__ Wd,
                                 const float* __restrict__ bd,
                                 float* __restrict__ out) {
    __shared__ __align__(16) char smem[65536];
    const int tid  = threadIdx.x;
    const int wid  = tid >> 6;
    const int lane = tid & 63;
    const int l    = lane & 15;
    const int quad = lane >> 4;
    const int b0   = blockIdx.x * MB;
    const int j    = wid * 16 + l;

    // ---------- prologue: B fragments staged through LDS (defeats remat-sinking) ----------
    _Float16* stage = (_Float16*)smem;      // [8][8][512] halves = 64 KB
    half8 bfrag[4][4];                       // wave 7 uses only bfrag[0] (= Wd cols)
#pragma unroll
    for (int pass = 0; pass < 2; ++pass) {
#pragma unroll
        for (int gg = 0; gg < 2; ++gg) {
            const int G = pass * 2 + gg;
#pragma unroll
            for (int kt = 0; kt < 4; ++kt) {
                half8 v;
#pragma unroll
                for (int jj = 0; jj < 8; ++jj) {
                    const int k = kt * 32 + quad * 8 + jj;
                    float w = 0.f;
                    if (wid < 7) {
                        if (j < HID) {
                            if (k < HID)            w = Wh[k * G4 + G * HID + j];
                            else if (k < HID + DIN) w = Wx[(k - HID) * G4 + G * HID + j];
                        }
                    } else if (G == 0) {
                        if (l < DIN && k < HID)     w = Wd[k * DIN + l];
                    }
                    v[jj] = (_Float16)w;
                }
                *(half8*)&stage[((wid * 8) + (gg * 4 + kt)) * 512 + lane * 8] = v;
            }
        }
        __syncthreads();
#pragma unroll
        for (int gg = 0; gg < 2; ++gg)
#pragma unroll
            for (int kt = 0; kt < 4; ++kt)
                bfrag[pass * 2 + gg][kt] =
                    *(half8*)&stage[((wid * 8) + (gg * 4 + kt)) * 512 + lane * 8];
        __syncthreads();
    }

    // persistent bias-C registers (C operand of the first MFMA in each chain)
    f32x4 biasC[4];
#pragma unroll
    for (int G = 0; G < 4; ++G) biasC[G] = (f32x4){0.f, 0.f, 0.f, 0.f};
    if (wid < 7) {
        if (j < HID) {
#pragma unroll
            for (int G = 0; G < 4; ++G) {
                const float bv = b[G * HID + j];
                biasC[G] = (f32x4){bv, bv, bv, bv};
            }
        }
    } else if (l < DIN) {
        const float bv = bd[l];
        biasC[0] = (f32x4){bv, bv, bv, bv};
    }

    // ---------- LDS after prologue: 4-row A dbuf (320B stride) + x chunk ----------
    _Float16 (*Ah)[MB][AROW] = (_Float16 (*)[MB][AROW])smem;     // 2*4*160*2 = 2560 B
    _Float16* xchunk = (_Float16*)(smem + 2560);                 // 64*48*2 = 6144 B

    auto refill = [&](int c) {    // x[c*64 .. +63] for 4 batches -> fp16 LDS
#pragma unroll
        for (int ii = 0; ii < 2; ++ii) {
            const int f = tid + NTHR * ii;
            if (f < (CHUNK * MB * DIN) / 4) {                    // 768 float4s
                const int m  = f / (CHUNK * DIN / 4);            // /192
                const int o  = f - m * (CHUNK * DIN / 4);
                const int tt = o / 3;
                const int dd = o - tt * 3;
                const float4 v = *(const float4*)(x +
                    ((size_t)(b0 + m) * T_LEN + c * CHUNK + tt) * DIN + dd * 4);
                half4_t h4;
                h4[0] = (_Float16)v.x; h4[1] = (_Float16)v.y;
                h4[2] = (_Float16)v.z; h4[3] = (_Float16)v.w;
                *(half4_t*)&xchunk[tt * (MB * DIN) + m * DIN + dd * 4] = h4;
            }
        }
    };

    for (int i = tid; i < (2 * MB * AROW) / 2; i += NTHR) ((int*)smem)[i] = 0;
    refill(0);
    __syncthreads();
    if (tid < MB * 3) {           // stage x[0]
        const int m = tid / 3, part = tid - (tid / 3) * 3;
        *(half4_t*)&Ah[0][m][HID + part * 4] =
            *(const half4_t*)&xchunk[m * DIN + part * 4];
    }
    __syncthreads();

    const bool gate_lane = (wid < 7) && (j < HID);
    const int  arow = l >> 2;
    const float L2E = 1.4426950408889634f;

    float c = 0.f;                // cell state (C-reg 0, batch = quad)
    float obuf[UNROLL];

#pragma unroll 1
    for (int tb = 0; tb < T_LEN / UNROLL; ++tb) {
#pragma unroll
        for (int it = 0; it < UNROLL; ++it) {
            const int t  = tb * UNROLL + it;     // always < T_LEN here
            const int p  = it & 1;               // compile-time parity
            const int pn = p ^ 1;

            if (it == UNROLL - 1) {
                // refill next 64-step chunk during step t=64k+63
                if (((tb + 1) & 7) == 0 && (tb + 1) < T_LEN / UNROLL) {
                    refill((tb + 1) >> 3);
                    __syncthreads();
                }
            }

            half8 a[4];
#pragma unroll
            for (int kt = 0; kt < 4; ++kt)
                a[kt] = *(const half8*)&Ah[p][arow][kt * 32 + quad * 8];

            if (wid < 7) {
                f32x4 acc[4];
                // kt outer / G inner; chain starts from biasC (no acc init)
#pragma unroll
                for (int kt = 0; kt < 4; ++kt)
#pragma unroll
                    for (int G = 0; G < 4; ++G)
                        acc[G] = __builtin_amdgcn_mfma_f32_16x16x32_f16(
                                     a[kt], bfrag[G][kt],
                                     (kt == 0) ? biasC[G] : acc[G], 0, 0, 0);

                if (gate_lane) {
                    // combined-reciprocal LSTM cell (reg 0 only)
                    const float ei = fast_exp2(-L2E * acc[0][0]);
                    const float ef = fast_exp2(-L2E * acc[1][0]);
                    const float eg = fast_exp2(-2.f * L2E * acc[2][0]);
                    const float eo = fast_exp2(-L2E * acc[3][0]);
                    const float gig = (1.f - eg) * fast_rcp((1.f + ei) * (1.f + eg));
                    const float gf  = fast_rcp(1.f + ef);
                    const float cn  = gf * c + gig;
                    c = cn;
                    const float ec = fast_exp2(-2.f * L2E * cn);
                    const float hv = (1.f - ec) * fast_rcp((1.f + eo) * (1.f + ec));
                    Ah[pn][quad][j] = (_Float16)hv;
                }
            } else {
                f32x4 accP;
#pragma unroll
                for (int kt = 0; kt < 4; ++kt)
                    accP = __builtin_amdgcn_mfma_f32_16x16x32_f16(
                               a[kt], bfrag[0][kt],
                               (kt == 0) ? biasC[0] : accP, 0, 0, 0);
                obuf[it] = accP[0];               // out row t-1, batch=quad, col=l
                if ((t + 1) < T_LEN && lane < MB * 3) {   // stage x[t+1]
                    const int m = lane / 3, part = lane - (lane / 3) * 3;
                    *(half4_t*)&Ah[pn][m][HID + part * 4] =
                        *(const half4_t*)&xchunk[((t + 1) & (CHUNK - 1)) * (MB * DIN)
                                                 + m * DIN + part * 4];
                }
            }
            __syncthreads();
        }
        if (wid == 7 && l < DIN) {
#pragma unroll
            for (int s = 0; s < UNROLL; ++s) {
                const int row = tb * UNROLL + s - 1;
                if (row >= 0)
                    out[((size_t)(b0 + quad) * T_LEN + row) * DIN + l] = obuf[s];
            }
        }
    }

    // ---------- epilogue: projection of h_{T-1} -> out row T-1 ----------
    if (wid == 7) {
        half8 a[4];
#pragma unroll
        for (int kt = 0; kt < 4; ++kt)
            a[kt] = *(const half8*)&Ah[0][arow][kt * 32 + quad * 8];
        f32x4 accP;
#pragma unroll
        for (int kt = 0; kt < 4; ++kt)
            accP = __builtin_amdgcn_mfma_f32_16x16x32_f16(
                       a[kt], bfrag[0][kt],
                       (kt == 0) ? biasC[0] : accP, 0, 0, 0);
        if (l < DIN)
            out[((size_t)(b0 + quad) * T_LEN + (T_LEN - 1)) * DIN + l] = accP[0];
    }
}

extern "C" void kernel_launch(void* const* d_in, const int* in_sizes, int n_in,
                              void* d_out, int out_size, void* d_ws, size_t ws_size,
                              hipStream_t stream) {
    const float* x  = (const float*)d_in[0];
    const float* Wx = (const float*)d_in[1];
    const float* Wh = (const float*)d_in[2];
    const float* b  = (const float*)d_in[3];
    const float* Wd = (const float*)d_in[4];
    const float* bd = (const float*)d_in[5];
    float* out = (float*)d_out;

    lstm_mfma_kernel<<<NBLK, NTHR, 0, stream>>>(x, Wx, Wh, b, Wd, bd, out);
}